// Round 1
// baseline (419.712 us; speedup 1.0000x reference)
//
#include <hip/hip_runtime.h>
#include <math.h>

#define B_ROWS 262144
#define PREP_BLOCKS 128
#define MAIN_BLOCKS 1408
#define TOTAL_BLOCKS (PREP_BLOCKS + MAIN_BLOCKS)   // 1536 = 256 CU x 6 resident
#define N_WAVES (MAIN_BLOCKS * 4)                  // 5632 wave streams
#define N_TILES (B_ROWS / 8)                       // 32768 tiles of 8 rows
#define TILE_F4 198                                // 8*99/4 float4 per tile

// ws uint-cell layout:
//  [0..9]    atomicMax of ~map(x)  -> global per-feature MIN   (memset 0)
//  [10..19]  atomicMax of  map(x)  -> global per-feature MAX   (memset 0)
//  [20] cm, [21] cf  (sex counts, atomicAdd)                   (memset 0)
//  [22] ready-counter (prep minmax done), [23] done-counter    (memset 0)
//  [24..223] hist 100 male + 100 female (integer atomicAdd)    (memset 0)
//  [256..]   C partials: 3 x MAIN_BLOCKS floats (fully overwritten)
#define WS_HIST 24
#define WS_C 256
#define WS_ZERO_CELLS 224

__device__ __forceinline__ unsigned int map_f(float x) {
  unsigned int b = __float_as_uint(x);
  return (b & 0x80000000u) ? ~b : (b | 0x80000000u);
}
__device__ __forceinline__ float unmap_f(unsigned int u) {
  unsigned int b = (u & 0x80000000u) ? (u ^ 0x80000000u) : ~u;
  return __uint_as_float(b);
}
__device__ __forceinline__ unsigned int aload(const unsigned int* p) {
  return __hip_atomic_load(p, __ATOMIC_RELAXED, __HIP_MEMORY_SCOPE_AGENT);
}
__device__ __forceinline__ float aloadf(const float* p) {
  return __hip_atomic_load(p, __ATOMIC_RELAXED, __HIP_MEMORY_SCOPE_AGENT);
}

// Issue one tile's loads: 4 global_load_lds DMAs (d -> LDS, linear dest) and
// 4 register loads (t). Exactly 8 vmem ops, always (tail ops are exec-masked
// but exec!=0 for every wave, and r3 uses a clamped in-bounds address).
__device__ __forceinline__ void issue_tile(const float* __restrict__ d,
                                           const float* __restrict__ t,
                                           int tile, int lane, float* lb,
                                           float4& r0, float4& r1,
                                           float4& r2, float4& r3) {
  const float4* dsp = (const float4*)d + (size_t)tile * TILE_F4;
  const float4* tsp = (const float4*)t + (size_t)tile * TILE_F4;
  __builtin_amdgcn_global_load_lds(
      (const __attribute__((address_space(1))) void*)(dsp + lane),
      (__attribute__((address_space(3))) void*)(lb), 16, 0, 0);
  __builtin_amdgcn_global_load_lds(
      (const __attribute__((address_space(1))) void*)(dsp + 64 + lane),
      (__attribute__((address_space(3))) void*)(lb + 256), 16, 0, 0);
  __builtin_amdgcn_global_load_lds(
      (const __attribute__((address_space(1))) void*)(dsp + 128 + lane),
      (__attribute__((address_space(3))) void*)(lb + 512), 16, 0, 0);
  if (lane < 6)
    __builtin_amdgcn_global_load_lds(
        (const __attribute__((address_space(1))) void*)(dsp + 192 + lane),
        (__attribute__((address_space(3))) void*)(lb + 768), 16, 0, 0);
  r0 = tsp[lane];
  r1 = tsp[64 + lane];
  r2 = tsp[128 + lane];
  r3 = tsp[192 + ((lane < 6) ? lane : 0)];   // clamped; garbage lanes unused
}

// One float4 chunk of mse/dot, plus all-64-lane exp written back in place.
template <int IT>
__device__ __forceinline__ void chunk(const float4* ld4, float4* st4, float4 tv,
                                      int lane, float& mse, float& dot) {
  int f = IT * 64 + lane;
  if (IT < 3 || lane < 6) {
    float4 xd = ld4[f];
    int e = f * 4;
    int c = e - (e / 99) * 99;               // magic-mul const divisor
    float dv[4] = {xd.x, xd.y, xd.z, xd.w};
    float tw[4] = {tv.x, tv.y, tv.z, tv.w};
#pragma unroll
    for (int k = 0; k < 4; k++) {
      int cc = c + k;
      if (cc >= 99) cc -= 99;
      bool cont = (cc == 0) | ((unsigned)(cc - 55) <= 2u);
      float diff = dv[k] - tw[k];
      if (cont) mse += diff * diff;
      else      dot += tw[k] * dv[k];
    }
    float4 ev;                                // vectorized exp: 64 lanes busy
    ev.x = __expf(xd.x); ev.y = __expf(xd.y);
    ev.z = __expf(xd.z); ev.w = __expf(xd.w);
    st4[f] = ev;                              // in-place: raw d already in regs
  }
}

__global__ __launch_bounds__(256, 6) void k_fused(const float* __restrict__ enc,
                                                  const float* __restrict__ d,
                                                  const float* __restrict__ t,
                                                  unsigned int* __restrict__ ws,
                                                  float* __restrict__ out) {
  __shared__ float sd[4][2][800];     // per-wave double-buffered d tiles (25.6 KB)
  __shared__ float red[16];
  __shared__ float mnv[10], wid[10];
  __shared__ unsigned int h[200];
  __shared__ float smn[4][10], smx[4][10];
  __shared__ unsigned int sc[4][2];
  __shared__ int lastflag;

  int tid = threadIdx.x, bid = blockIdx.x;
  int wave = tid >> 6, lane = tid & 63;

  if (bid < PREP_BLOCKS) {
    // ================= prep: pass 1 minmax over data_encoded =================
    const float4* e4 = (const float4*)enc;
    float mn[10], mx[10];
#pragma unroll
    for (int j = 0; j < 10; j++) { mn[j] = 1e30f; mx[j] = -1e30f; }
    unsigned int cm = 0, cf = 0;
#pragma unroll
    for (int i = 0; i < 8; i++) {
      size_t g = (size_t)bid * 2048 + i * 256 + tid;
      float4 a = e4[g * 3 + 0], b = e4[g * 3 + 1], c = e4[g * 3 + 2];
      float v[12] = {a.x,a.y,a.z,a.w,b.x,b.y,b.z,b.w,c.x,c.y,c.z,c.w};
#pragma unroll
      for (int j = 0; j < 10; j++) { mn[j] = fminf(mn[j], v[j]); mx[j] = fmaxf(mx[j], v[j]); }
      cm += (v[11] == 0.0f); cf += (v[11] == 1.0f);
    }
#pragma unroll
    for (int off = 32; off; off >>= 1) {
#pragma unroll
      for (int j = 0; j < 10; j++) {
        mn[j] = fminf(mn[j], __shfl_xor(mn[j], off));
        mx[j] = fmaxf(mx[j], __shfl_xor(mx[j], off));
      }
      cm += __shfl_xor(cm, off); cf += __shfl_xor(cf, off);
    }
    if (lane == 0) {
#pragma unroll
      for (int j = 0; j < 10; j++) { smn[wave][j] = mn[j]; smx[wave][j] = mx[j]; }
      sc[wave][0] = cm; sc[wave][1] = cf;
    }
    __syncthreads();
    if (tid < 10) {
      float m = fminf(fminf(smn[0][tid], smn[1][tid]), fminf(smn[2][tid], smn[3][tid]));
      atomicMax(ws + tid, ~map_f(m));          // min via max of ~map, init 0
    } else if (tid < 20) {
      int j = tid - 10;
      float m = fmaxf(fmaxf(smx[0][j], smx[1][j]), fmaxf(smx[2][j], smx[3][j]));
      atomicMax(ws + tid, map_f(m));
    } else if (tid < 22) {
      int j = tid - 20;
      atomicAdd(ws + 20 + j, sc[0][j] + sc[1][j] + sc[2][j] + sc[3][j]);
    }
    __syncthreads();                           // barrier drains the atomics
    if (tid == 0) {
      __threadfence();
      __hip_atomic_fetch_add(ws + 22, 1u, __ATOMIC_ACQ_REL, __HIP_MEMORY_SCOPE_AGENT);
      // spin until all 128 prep blocks contributed (prep-only dependency:
      // main blocks never wait -> no deadlock regardless of dispatch order)
      while (__hip_atomic_load(ws + 22, __ATOMIC_ACQUIRE, __HIP_MEMORY_SCOPE_AGENT) < PREP_BLOCKS)
        __builtin_amdgcn_s_sleep(2);
    }
    __syncthreads();
    // ================= prep: pass 2 histogram (enc is L2-hot) ================
    if (tid < 10) {
      unsigned int nm = aload(ws + tid);
      unsigned int xm = aload(ws + 10 + tid);
      float mn_ = unmap_f(~nm);
      mnv[tid] = mn_;
      wid[tid] = fmaxf(unmap_f(xm) - mn_, 1e-12f);
    }
    for (int i = tid; i < 200; i += 256) h[i] = 0u;
    __syncthreads();
#pragma unroll
    for (int i = 0; i < 8; i++) {
      size_t g = (size_t)bid * 2048 + i * 256 + tid;
      float4 a = e4[g * 3 + 0], b = e4[g * 3 + 1], c = e4[g * 3 + 2];
      float v[12] = {a.x,a.y,a.z,a.w,b.x,b.y,b.z,b.w,c.x,c.y,c.z,c.w};
      int base = (v[11] == 0.0f) ? 0 : ((v[11] == 1.0f) ? 100 : -1);
      if (base >= 0) {
#pragma unroll
        for (int cc2 = 0; cc2 < 10; cc2++) {
          float tt = (v[cc2] - mnv[cc2]) / wid[cc2] * 10.0f;   // reference op order
          int bi = min(max((int)floorf(tt), 0), 9);
          atomicAdd(&h[base + cc2 * 10 + bi], 1u);
        }
      }
    }
    __syncthreads();
    if (tid < 200) atomicAdd(ws + WS_HIST + tid, h[tid]);      // integer: deterministic
  } else {
    // ================= main: pipelined streaming over d/t ====================
    int gw = (bid - PREP_BLOCKS) * 4 + wave;
    float mse = 0.f, dot = 0.f, ce = 0.f;
    float4 tA0, tA1, tA2, tA3, tB0, tB1, tB2, tB3;
    int p = 0;
    int tile = gw;
    issue_tile(d, t, tile, lane, sd[wave][0], tA0, tA1, tA2, tA3);
    while (true) {
      float* cb = sd[wave][p];
      int next = tile + N_WAVES;
      bool hn = next < N_TILES;
      if (hn) {
        issue_tile(d, t, next, lane, sd[wave][p ^ 1], tB0, tB1, tB2, tB3);
        // counted wait: 8 newest (next tile) stay in flight; current tile's
        // 8 are the oldest and vmem retires in order -> fully drained.
        asm volatile("s_waitcnt vmcnt(8)" ::: "memory");
      } else {
        asm volatile("s_waitcnt vmcnt(0)" ::: "memory");
      }
      __builtin_amdgcn_sched_barrier(0);
      const float4* ld4 = (const float4*)cb;
      float4* st4 = (float4*)cb;
      chunk<0>(ld4, st4, tA0, lane, mse, dot);
      chunk<1>(ld4, st4, tA1, lane, mse, dot);
      chunk<2>(ld4, st4, tA2, lane, mse, dot);
      chunk<3>(ld4, st4, tA3, lane, mse, dot);
      asm volatile("s_waitcnt lgkmcnt(0)" ::: "memory");  // E writes visible
      __builtin_amdgcn_sched_barrier(0);
      // LSE from precomputed E: pure full-rate LDS reads + adds (no trans ops)
      if (lane < 16) {
        const float* row = cb + (lane >> 1) * 99;
        float Z;
        if ((lane & 1) == 0) {                // blocks (1,8)(8,24)(24,31)(31,45)(45,51)
          Z = 0.f;
#pragma unroll
          for (int c = 1; c < 8; c++) Z += row[c];
          ce += __logf(Z);
          Z = 0.f;
#pragma unroll
          for (int c = 8; c < 24; c++) Z += row[c];
          ce += __logf(Z);
          Z = 0.f;
#pragma unroll
          for (int c = 24; c < 31; c++) Z += row[c];
          ce += __logf(Z);
          Z = 0.f;
#pragma unroll
          for (int c = 31; c < 45; c++) Z += row[c];
          ce += __logf(Z);
          Z = 0.f;
#pragma unroll
          for (int c = 45; c < 51; c++) Z += row[c];
          ce += __logf(Z);
        } else {                              // blocks (51,53)(53,55)(58,99)
          Z = 0.f;
#pragma unroll
          for (int c = 51; c < 53; c++) Z += row[c];
          ce += __logf(Z);
          Z = 0.f;
#pragma unroll
          for (int c = 53; c < 55; c++) Z += row[c];
          ce += __logf(Z);
          float Za = 0.f, Zb = 0.f;           // split 41-chain to 2 accumulators
#pragma unroll
          for (int c = 58; c < 78; c++) Za += row[c];
#pragma unroll
          for (int c = 78; c < 99; c++) Zb += row[c];
          ce += __logf(Za + Zb);
        }
      }
      if (!hn) break;
      tile = next;
      p ^= 1;
      tA0 = tB0; tA1 = tB1; tA2 = tB2; tA3 = tB3;
    }
    // per-block reduction of the 3 partials
#pragma unroll
    for (int off = 32; off; off >>= 1) {
      mse += __shfl_xor(mse, off);
      dot += __shfl_xor(dot, off);
      ce  += __shfl_xor(ce,  off);
    }
    if (lane == 0) { red[wave] = mse; red[4 + wave] = dot; red[8 + wave] = ce; }
    __syncthreads();
    if (tid == 0) {
      float* C = (float*)(ws + WS_C);
      int mb = bid - PREP_BLOCKS;
      C[mb]                   = red[0] + red[1] + red[2]  + red[3];
      C[MAIN_BLOCKS + mb]     = red[4] + red[5] + red[6]  + red[7];
      C[2 * MAIN_BLOCKS + mb] = red[8] + red[9] + red[10] + red[11];
    }
  }

  // ================= done-counter election; last block finalizes =============
  __syncthreads();
  if (tid == 0) {
    __threadfence();
    unsigned int old = __hip_atomic_fetch_add(ws + 23, 1u, __ATOMIC_ACQ_REL,
                                              __HIP_MEMORY_SCOPE_AGENT);
    lastflag = (old == (unsigned int)(TOTAL_BLOCKS - 1)) ? 1 : 0;
  }
  __syncthreads();
  if (lastflag == 0) return;
  __threadfence();

  const float* C = (const float*)(ws + WS_C);
  float msum = 0.f, dsum = 0.f, csum = 0.f;
  for (int i = tid; i < MAIN_BLOCKS; i += 256) {
    msum += aloadf(C + i);
    dsum += aloadf(C + MAIN_BLOCKS + i);
    csum += aloadf(C + 2 * MAIN_BLOCKS + i);
  }
  float term = 0.f;
  if (tid < 100) {
    float cmf = fmaxf((float)aload(ws + 20), 1.0f);
    float cff = fmaxf((float)aload(ws + 21), 1.0f);
    float mc = (float)aload(ws + WS_HIST + tid);
    float fc = (float)aload(ws + WS_HIST + 100 + tid);
    if (mc > 0.f && fc > 0.f) {
      float pp = mc / cmf, qq = fc / cff;
      term = pp * logf(pp / qq);
    }
  }
#pragma unroll
  for (int off = 32; off; off >>= 1) {
    msum += __shfl_xor(msum, off);
    dsum += __shfl_xor(dsum, off);
    csum += __shfl_xor(csum, off);
    term += __shfl_xor(term, off);
  }
  if (lane == 0) {
    red[wave] = msum; red[4 + wave] = dsum; red[8 + wave] = csum; red[12 + wave] = term;
  }
  __syncthreads();
  if (tid == 0) {
    const float invB = 1.0f / (float)B_ROWS;
    float mse = (red[0] + red[1] + red[2] + red[3]) * invB;
    float dd  = red[4] + red[5] + red[6] + red[7];
    float cc  = red[8] + red[9] + red[10] + red[11];
    float ce  = (cc - dd) * invB;
    float akld = 0.5f * (red[12] + red[13] + red[14] + red[15]);
    out[0] = 0.5f * (mse + ce) + akld;
    out[1] = mse;
    out[2] = ce;
    out[3] = akld;
  }
}

extern "C" void kernel_launch(void* const* d_in, const int* in_sizes, int n_in,
                              void* d_out, int out_size, void* d_ws, size_t ws_size,
                              hipStream_t stream) {
  const float* enc = (const float*)d_in[0];   // data_encoded (B,12)
  const float* dec = (const float*)d_in[1];   // data_decoded (B,99)
  const float* tru = (const float*)d_in[2];   // data_true    (B,99)
  unsigned int* ws = (unsigned int*)d_ws;
  float* out = (float*)d_out;

  hipMemsetAsync(d_ws, 0, WS_ZERO_CELLS * sizeof(unsigned int), stream);
  hipLaunchKernelGGL(k_fused, dim3(TOTAL_BLOCKS), dim3(256), 0, stream,
                     enc, dec, tru, ws, out);
}

// Round 2
// 404.122 us; speedup vs baseline: 1.0386x; 1.0386x over previous
//
#include <hip/hip_runtime.h>
#include <math.h>

#define B_ROWS 262144
#define PREP_BLOCKS 256
#define MAIN_BLOCKS 1280
#define TOTAL_BLOCKS (PREP_BLOCKS + MAIN_BLOCKS)   // 1536 = 256 CU x 6 resident
#define ROWS_PER_PREP 1024                         // 262144 / 256
#define TILE_ROWS 4
#define N_TILES 65536                              // 262144 / 4
#define TILE_F4 99                                 // 4*99/4 float4 per array
#define MAIN_STREAMS (MAIN_BLOCKS * 4)             // 5120 streams x 12 tiles
#define PREP_STREAMS (PREP_BLOCKS * 4)             // 1024 streams x 4 tiles
#define MAIN_TILE_LIMIT 61440                      // 5120 * 12

// ws uint-cell layout:
//  [0..9]    atomicMax of ~map(x)  -> global per-feature MIN   (memset 0)
//  [10..19]  atomicMax of  map(x)  -> global per-feature MAX   (memset 0)
//  [20] cm, [21] cf  (sex counts, atomicAdd)                   (memset 0)
//  [22] ready-counter (prep minmax done), [23] done-counter    (memset 0)
//  [24..223] hist 100 male + 100 female (integer atomicAdd)    (memset 0)
//  [256..]   C partials: 3 x TOTAL_BLOCKS floats (fully overwritten)
#define WS_HIST 24
#define WS_C 256
#define WS_ZERO_CELLS 224

__device__ __forceinline__ unsigned int map_f(float x) {
  unsigned int b = __float_as_uint(x);
  return (b & 0x80000000u) ? ~b : (b | 0x80000000u);
}
__device__ __forceinline__ float unmap_f(unsigned int u) {
  unsigned int b = (u & 0x80000000u) ? (u ^ 0x80000000u) : ~u;
  return __uint_as_float(b);
}
__device__ __forceinline__ unsigned int aload(const unsigned int* p) {
  return __hip_atomic_load(p, __ATOMIC_RELAXED, __HIP_MEMORY_SCOPE_AGENT);
}
__device__ __forceinline__ float aloadf(const float* p) {
  return __hip_atomic_load(p, __ATOMIC_RELAXED, __HIP_MEMORY_SCOPE_AGENT);
}

// Stage one 4-row tile: d and t both via global_load_lds (linear dest,
// wave-uniform base + lane*16). Exactly 4 vmem instructions per call
// (2 full + 2 exec-masked to lanes 0..34; exec never 0 -> always issued).
__device__ __forceinline__ void issue_tile(const float* __restrict__ d,
                                           const float* __restrict__ t,
                                           int tile, int lane,
                                           float4* bd, float4* bt) {
  const float4* dsp = (const float4*)d + (size_t)tile * TILE_F4;
  const float4* tsp = (const float4*)t + (size_t)tile * TILE_F4;
  __builtin_amdgcn_global_load_lds(
      (const __attribute__((address_space(1))) void*)(dsp + lane),
      (__attribute__((address_space(3))) void*)bd, 16, 0, 0);
  __builtin_amdgcn_global_load_lds(
      (const __attribute__((address_space(1))) void*)(tsp + lane),
      (__attribute__((address_space(3))) void*)bt, 16, 0, 0);
  if (lane < 35) {
    __builtin_amdgcn_global_load_lds(
        (const __attribute__((address_space(1))) void*)(dsp + 64 + lane),
        (__attribute__((address_space(3))) void*)(bd + 64), 16, 0, 0);
    __builtin_amdgcn_global_load_lds(
        (const __attribute__((address_space(1))) void*)(tsp + 64 + lane),
        (__attribute__((address_space(3))) void*)(bt + 64), 16, 0, 0);
  }
}

// One float4 chunk of mse/dot (both operands from LDS), plus all-64-lane exp
// written back in place (raw d already in regs; LSE needs only exp values).
template <int IT>
__device__ __forceinline__ void chunk(float4* bd, const float4* bt, int lane,
                                      float& mse, float& dot) {
  if (IT == 0 || lane < 35) {
    int f = IT * 64 + lane;
    float4 xd = bd[f];
    float4 xt = bt[f];
    int e = f * 4;
    int c = e - (e / 99) * 99;               // magic-mul const divisor, e<396
    float dv[4] = {xd.x, xd.y, xd.z, xd.w};
    float tw[4] = {xt.x, xt.y, xt.z, xt.w};
#pragma unroll
    for (int k = 0; k < 4; k++) {
      int cc = c + k;
      if (cc >= 99) cc -= 99;
      bool cont = (cc == 0) | ((unsigned)(cc - 55) <= 2u);
      float diff = dv[k] - tw[k];
      if (cont) mse += diff * diff;
      else      dot += tw[k] * dv[k];
    }
    float4 ev;                                // vectorized exp: 64 lanes busy
    ev.x = __expf(xd.x); ev.y = __expf(xd.y);
    ev.z = __expf(xd.z); ev.w = __expf(xd.w);
    bd[f] = ev;
  }
}

// LSE over precomputed exp: 2 lanes/row (even: blocks in cols 1..51,
// odd: cols 51..99), pure full-rate LDS scalar reads + adds.
__device__ __forceinline__ void lse_rows(const float* bd, int lane, float& ce) {
  if (lane < 2 * TILE_ROWS) {
    const float* row = bd + (lane >> 1) * 99;
    float Z;
    if ((lane & 1) == 0) {                // blocks (1,8)(8,24)(24,31)(31,45)(45,51)
      Z = 0.f;
#pragma unroll
      for (int c = 1; c < 8; c++) Z += row[c];
      ce += __logf(Z);
      Z = 0.f;
#pragma unroll
      for (int c = 8; c < 24; c++) Z += row[c];
      ce += __logf(Z);
      Z = 0.f;
#pragma unroll
      for (int c = 24; c < 31; c++) Z += row[c];
      ce += __logf(Z);
      Z = 0.f;
#pragma unroll
      for (int c = 31; c < 45; c++) Z += row[c];
      ce += __logf(Z);
      Z = 0.f;
#pragma unroll
      for (int c = 45; c < 51; c++) Z += row[c];
      ce += __logf(Z);
    } else {                              // blocks (51,53)(53,55)(58,99)
      Z = 0.f;
#pragma unroll
      for (int c = 51; c < 53; c++) Z += row[c];
      ce += __logf(Z);
      Z = 0.f;
#pragma unroll
      for (int c = 53; c < 55; c++) Z += row[c];
      ce += __logf(Z);
      float Za = 0.f, Zb = 0.f;           // split 41-chain into 2 accumulators
#pragma unroll
      for (int c = 58; c < 78; c++) Za += row[c];
#pragma unroll
      for (int c = 78; c < 99; c++) Zb += row[c];
      ce += __logf(Za + Zb);
    }
  }
}

// Streaming loop: all staged data in LDS, double-buffered, depth-1 prefetch
// with counted vmcnt(4) (current tile's 4 DMAs are the oldest outstanding;
// vmem retires in order -> fully drained; next tile's 4 stay in flight).
// NO registers carried conditionally across iterations (round-1 spill lesson).
__device__ __forceinline__ void stream_tiles(const float* __restrict__ d,
                                             const float* __restrict__ t,
                                             float4* buf,   // [2][2][100] f4
                                             int start, int stride, int limit,
                                             int lane,
                                             float& mse, float& dot, float& ce) {
  int p = 0;
  issue_tile(d, t, start, lane, buf, buf + 100);
  for (int tile = start; tile < limit; tile += stride) {
    int next = tile + stride;
    float4* bd = buf + p * 200;
    float4* bt = bd + 100;
    if (next < limit) {
      issue_tile(d, t, next, lane, buf + (p ^ 1) * 200, buf + (p ^ 1) * 200 + 100);
      asm volatile("s_waitcnt vmcnt(4)" ::: "memory");
    } else {
      asm volatile("s_waitcnt vmcnt(0)" ::: "memory");
    }
    __builtin_amdgcn_sched_barrier(0);
    chunk<0>(bd, bt, lane, mse, dot);
    chunk<1>(bd, bt, lane, mse, dot);
    asm volatile("s_waitcnt lgkmcnt(0)" ::: "memory");  // exp writes visible
    __builtin_amdgcn_sched_barrier(0);
    lse_rows((const float*)bd, lane, ce);
    p ^= 1;
  }
}

__global__ __launch_bounds__(256, 6) void k_fused(const float* __restrict__ enc,
                                                  const float* __restrict__ d,
                                                  const float* __restrict__ t,
                                                  unsigned int* __restrict__ ws,
                                                  float* __restrict__ out) {
  __shared__ float4 sd4[4][2][2][100];  // per-wave dbuf {d,t} tiles (25.6 KB)
  __shared__ float red[16];
  __shared__ float mnv[10], wid[10];
  __shared__ unsigned int h[200];
  __shared__ float smn[4][10], smx[4][10];
  __shared__ unsigned int sc[4][2];
  __shared__ int lastflag;

  int tid = threadIdx.x, bid = blockIdx.x;
  int wave = tid >> 6, lane = tid & 63;
  float4* buf = &sd4[wave][0][0][0];

  float mse = 0.f, dot = 0.f, ce = 0.f;

  if (bid < PREP_BLOCKS) {
    // ---------- prep pass 1: minmax + sex counts over data_encoded ----------
    const float4* e4 = (const float4*)enc;
    float mn[10], mx[10];
#pragma unroll
    for (int j = 0; j < 10; j++) { mn[j] = 1e30f; mx[j] = -1e30f; }
    unsigned int cm = 0, cf = 0;
#pragma unroll
    for (int i = 0; i < 4; i++) {
      size_t g = (size_t)bid * ROWS_PER_PREP + i * 256 + tid;
      float4 a = e4[g * 3 + 0], b = e4[g * 3 + 1], c = e4[g * 3 + 2];
      float v[12] = {a.x,a.y,a.z,a.w,b.x,b.y,b.z,b.w,c.x,c.y,c.z,c.w};
#pragma unroll
      for (int j = 0; j < 10; j++) { mn[j] = fminf(mn[j], v[j]); mx[j] = fmaxf(mx[j], v[j]); }
      cm += (v[11] == 0.0f); cf += (v[11] == 1.0f);
    }
#pragma unroll
    for (int off = 32; off; off >>= 1) {
#pragma unroll
      for (int j = 0; j < 10; j++) {
        mn[j] = fminf(mn[j], __shfl_xor(mn[j], off));
        mx[j] = fmaxf(mx[j], __shfl_xor(mx[j], off));
      }
      cm += __shfl_xor(cm, off); cf += __shfl_xor(cf, off);
    }
    if (lane == 0) {
#pragma unroll
      for (int j = 0; j < 10; j++) { smn[wave][j] = mn[j]; smx[wave][j] = mx[j]; }
      sc[wave][0] = cm; sc[wave][1] = cf;
    }
    __syncthreads();
    if (tid < 10) {
      float m = fminf(fminf(smn[0][tid], smn[1][tid]), fminf(smn[2][tid], smn[3][tid]));
      atomicMax(ws + tid, ~map_f(m));          // min via max of ~map, init 0
    } else if (tid < 20) {
      int j = tid - 10;
      float m = fmaxf(fmaxf(smx[0][j], smx[1][j]), fmaxf(smx[2][j], smx[3][j]));
      atomicMax(ws + tid, map_f(m));
    } else if (tid < 22) {
      int j = tid - 20;
      atomicAdd(ws + 20 + j, sc[0][j] + sc[1][j] + sc[2][j] + sc[3][j]);
    }
    __syncthreads();                           // block's atomics all issued
    if (tid == 0) {
      __threadfence();
      __hip_atomic_fetch_add(ws + 22, 1u, __ATOMIC_ACQ_REL, __HIP_MEMORY_SCOPE_AGENT);
    }
    // ---------- prep streams its 4-tile share (no gate on this path) --------
    int gw = bid * 4 + wave;
    stream_tiles(d, t, buf, MAIN_TILE_LIMIT + gw, PREP_STREAMS, N_TILES,
                 lane, mse, dot, ce);
    // ---------- gate AFTER streaming (off critical path, deadlock-free:
    // spinners never occupy all slots; main blocks terminate and free slots,
    // so any not-yet-resident prep block eventually runs and increments) -----
    if (tid == 0) {
      while (__hip_atomic_load(ws + 22, __ATOMIC_ACQUIRE, __HIP_MEMORY_SCOPE_AGENT)
             < PREP_BLOCKS)
        __builtin_amdgcn_s_sleep(2);
    }
    __syncthreads();
    // ---------- prep pass 2: histogram with global min/max ------------------
    if (tid < 10) {
      unsigned int nm = aload(ws + tid);
      unsigned int xm = aload(ws + 10 + tid);
      float mn_ = unmap_f(~nm);
      mnv[tid] = mn_;
      wid[tid] = fmaxf(unmap_f(xm) - mn_, 1e-12f);
    }
    for (int i = tid; i < 200; i += 256) h[i] = 0u;
    __syncthreads();
#pragma unroll
    for (int i = 0; i < 4; i++) {
      size_t g = (size_t)bid * ROWS_PER_PREP + i * 256 + tid;
      float4 a = e4[g * 3 + 0], b = e4[g * 3 + 1], c = e4[g * 3 + 2];
      float v[12] = {a.x,a.y,a.z,a.w,b.x,b.y,b.z,b.w,c.x,c.y,c.z,c.w};
      int base = (v[11] == 0.0f) ? 0 : ((v[11] == 1.0f) ? 100 : -1);
      if (base >= 0) {
#pragma unroll
        for (int cc2 = 0; cc2 < 10; cc2++) {
          float tt = (v[cc2] - mnv[cc2]) / wid[cc2] * 10.0f;   // reference op order
          int bi = min(max((int)floorf(tt), 0), 9);
          atomicAdd(&h[base + cc2 * 10 + bi], 1u);
        }
      }
    }
    __syncthreads();
    if (tid < 200) atomicAdd(ws + WS_HIST + tid, h[tid]);      // deterministic
  } else {
    // ---------- main: 12-tile streams ---------------------------------------
    int gw = (bid - PREP_BLOCKS) * 4 + wave;
    stream_tiles(d, t, buf, gw, MAIN_STREAMS, MAIN_TILE_LIMIT,
                 lane, mse, dot, ce);
  }

  // ---------- per-block reduction of streamed partials (all 1536 blocks) ----
#pragma unroll
  for (int off = 32; off; off >>= 1) {
    mse += __shfl_xor(mse, off);
    dot += __shfl_xor(dot, off);
    ce  += __shfl_xor(ce,  off);
  }
  if (lane == 0) { red[wave] = mse; red[4 + wave] = dot; red[8 + wave] = ce; }
  __syncthreads();
  if (tid == 0) {
    float* C = (float*)(ws + WS_C);
    C[bid]                    = red[0] + red[1] + red[2]  + red[3];
    C[TOTAL_BLOCKS + bid]     = red[4] + red[5] + red[6]  + red[7];
    C[2 * TOTAL_BLOCKS + bid] = red[8] + red[9] + red[10] + red[11];
  }

  // ---------- done-counter election; globally-last block finalizes ----------
  __syncthreads();
  if (tid == 0) {
    __threadfence();
    unsigned int old = __hip_atomic_fetch_add(ws + 23, 1u, __ATOMIC_ACQ_REL,
                                              __HIP_MEMORY_SCOPE_AGENT);
    lastflag = (old == (unsigned int)(TOTAL_BLOCKS - 1)) ? 1 : 0;
  }
  __syncthreads();
  if (lastflag == 0) return;
  __threadfence();

  const float* C = (const float*)(ws + WS_C);
  float msum = 0.f, dsum = 0.f, csum = 0.f;
  for (int i = tid; i < TOTAL_BLOCKS; i += 256) {
    msum += aloadf(C + i);
    dsum += aloadf(C + TOTAL_BLOCKS + i);
    csum += aloadf(C + 2 * TOTAL_BLOCKS + i);
  }
  float term = 0.f;
  if (tid < 100) {
    float cmf = fmaxf((float)aload(ws + 20), 1.0f);
    float cff = fmaxf((float)aload(ws + 21), 1.0f);
    float mc = (float)aload(ws + WS_HIST + tid);
    float fc = (float)aload(ws + WS_HIST + 100 + tid);
    if (mc > 0.f && fc > 0.f) {
      float pp = mc / cmf, qq = fc / cff;
      term = pp * logf(pp / qq);
    }
  }
#pragma unroll
  for (int off = 32; off; off >>= 1) {
    msum += __shfl_xor(msum, off);
    dsum += __shfl_xor(dsum, off);
    csum += __shfl_xor(csum, off);
    term += __shfl_xor(term, off);
  }
  if (lane == 0) {
    red[wave] = msum; red[4 + wave] = dsum; red[8 + wave] = csum; red[12 + wave] = term;
  }
  __syncthreads();
  if (tid == 0) {
    const float invB = 1.0f / (float)B_ROWS;
    float mse_ = (red[0] + red[1] + red[2] + red[3]) * invB;
    float dd   = red[4] + red[5] + red[6] + red[7];
    float cc   = red[8] + red[9] + red[10] + red[11];
    float ce_  = (cc - dd) * invB;
    float akld = 0.5f * (red[12] + red[13] + red[14] + red[15]);
    out[0] = 0.5f * (mse_ + ce_) + akld;
    out[1] = mse_;
    out[2] = ce_;
    out[3] = akld;
  }
}

extern "C" void kernel_launch(void* const* d_in, const int* in_sizes, int n_in,
                              void* d_out, int out_size, void* d_ws, size_t ws_size,
                              hipStream_t stream) {
  const float* enc = (const float*)d_in[0];   // data_encoded (B,12)
  const float* dec = (const float*)d_in[1];   // data_decoded (B,99)
  const float* tru = (const float*)d_in[2];   // data_true    (B,99)
  unsigned int* ws = (unsigned int*)d_ws;
  float* out = (float*)d_out;

  hipMemsetAsync(d_ws, 0, WS_ZERO_CELLS * sizeof(unsigned int), stream);
  hipLaunchKernelGGL(k_fused, dim3(TOTAL_BLOCKS), dim3(256), 0, stream,
                     enc, dec, tru, ws, out);
}